// Round 7
// baseline (51.903 us; speedup 1.0000x reference)
//
#include <hip/hip_runtime.h>
#include <stdint.h>

// Problem constants
#define NBATCH 1024
#define NQ 300
#define NC 80
#define QC 24000       // NQ * NC floats per batch
#define NF4 6000       // QC / 4
#define TOPK 300
#define RSEL 384u      // fast-path lower guard / slow-path select rank
#define NT 512         // threads per block (8 waves)
#define NB1 2048       // slow-path coarse histogram buckets (key bits [31:21])
#define SH1 21
#define SH2 13         // slow-path refine bucket = (key >> 13) & 0xFF
#define SELCAP 2048    // candidate buffer
#define FINCAP 768     // finalist buffer / fast-path upper guard
#define TAIL 368       // threads with a valid 12th float4 (6000 - 11*512)
#define THRESH 2.0f    // prefilter: candidate iff logit >= 2.0 (E[cnt]=546, sigma=23)

// order-preserving f32-bits -> u32 key (branchless)
__device__ __forceinline__ uint32_t xform(uint32_t u) {
    return u ^ (uint32_t)(((int32_t)u >> 31) | 0x80000000);
}

__device__ __forceinline__ void push4(float4 v, uint32_t i4,
                                      uint64_t* __restrict__ sel,
                                      uint32_t* __restrict__ cnt_p) {
    float f[4] = { v.x, v.y, v.z, v.w };
#pragma unroll
    for (int c = 0; c < 4; ++c) {
        if (f[c] >= THRESH) {                     // raw float compare (1 op common path)
            uint32_t key = xform(__float_as_uint(f[c]));
            uint32_t pos = atomicAdd(cnt_p, 1u);  // compiler coalesces per-wave
            uint32_t idx = 4u * i4 + (uint32_t)c;
            if (pos < SELCAP)
                sel[pos] = ((uint64_t)key << 32) | (uint64_t)(0xFFFFFFFFu - idx);
        }
    }
}

// ---------------------------------------------------------------------------
// pick<NB,ZERO> (slow path only): hist[NB] finalized -> bucket from the top
// containing the rem-th largest + residual inside it. ZERO re-zeroes hist.
// ---------------------------------------------------------------------------
template<int NB, bool ZERO>
__device__ __forceinline__ void pick(uint32_t* __restrict__ hist,
                                     uint32_t* __restrict__ part,
                                     uint32_t* __restrict__ gsufx,
                                     uint32_t* __restrict__ misc,
                                     int tid, uint32_t rem,
                                     uint32_t* bucket_out, uint32_t* rem_out) {
    constexpr int G = (NB >= NT) ? (NB / NT) : 1;
    const int base = tid * G;
    uint32_t h[G];
    uint32_t s = 0;
    if (base < NB) {
#pragma unroll
        for (int u = 0; u < G; ++u) { h[u] = hist[base + u]; s += h[u]; }
        if (ZERO) {
#pragma unroll
            for (int u = 0; u < G; ++u) hist[base + u] = 0;
        }
    } else {
#pragma unroll
        for (int u = 0; u < G; ++u) h[u] = 0;
    }
    part[tid] = s;
    __syncthreads();

    if (tid < 64) {
        uint32_t gs = 0;
#pragma unroll
        for (int u = 0; u < 8; ++u) gs += part[(tid << 3) + u];
        uint32_t S = gs;
#pragma unroll
        for (int off = 1; off < 64; off <<= 1) {
            uint32_t v = __shfl_down(S, off, 64);
            if (tid + off < 64) S += v;
        }
        gsufx[tid] = S;
        if (tid == 0) gsufx[64] = 0;
    }
    __syncthreads();

    const int g8 = tid >> 3;
    uint32_t A = gsufx[g8 + 1];
    for (int t2 = tid + 1; t2 < ((g8 + 1) << 3); ++t2) A += part[t2];
    if (base < NB && A < rem && A + s >= rem) {
        uint32_t acc = 0, bsel = (uint32_t)base, r = 1;
#pragma unroll
        for (int u = G - 1; u >= 0; --u) {
            if (A + acc + h[u] >= rem) { bsel = (uint32_t)(base + u); r = rem - A - acc; break; }
            acc += h[u];
        }
        misc[0] = bsel;
        misc[1] = r;
    }
    __syncthreads();
    *bucket_out = misc[0];
    *rem_out    = misc[1];
}

__global__ void __launch_bounds__(NT, 6)   // 3 blocks/CU, VGPR cap ~84
rtdetr_post_kernel(const float* __restrict__ logits, const float* __restrict__ pboxes,
                   const float* __restrict__ sizes, float* __restrict__ out) {
    __shared__ __align__(16) uint32_t hist[NB1];   // 8KB (slow path only)
    __shared__ uint64_t sel[SELCAP];               // 16KB candidates
    __shared__ uint32_t part[NT];                  // 2KB (slow path only)
    __shared__ uint32_t gsufx[65];
    __shared__ uint32_t misc[4];
    uint64_t* sel2 = reinterpret_cast<uint64_t*>(&hist[512]);  // 768 u64 overlay

    const int tid = threadIdx.x;
    const int b   = blockIdx.x;
    const float4* lg4 = reinterpret_cast<const float4*>(logits + (size_t)b * QC);

    // ---- full-tile prefetch: issue all 12 guarded loads before anything ----
    float4 va[6], vb[6];
#pragma unroll
    for (int k = 0; k < 6; ++k) va[k] = lg4[tid + (k << 9)];
#pragma unroll
    for (int k = 0; k < 6; ++k)
        if (k < 5 || tid < TAIL) vb[k] = lg4[tid + ((k + 6) << 9)];
    __builtin_amdgcn_sched_barrier(0);             // keep loads clustered up front

    if (tid == 0) { misc[2] = 0; misc[3] = 0; }
    __syncthreads();                               // also drains the 12 loads (vmcnt(0))

    // ---- stream phase: pure register compute + rare LDS push ----
#pragma unroll
    for (int k = 0; k < 6; ++k)
        push4(va[k], (uint32_t)(tid + (k << 9)), sel, &misc[2]);
#pragma unroll
    for (int k = 0; k < 6; ++k)
        if (k < 5 || tid < TAIL)
            push4(vb[k], (uint32_t)(tid + ((k + 6) << 9)), sel, &misc[2]);
    __syncthreads();

    const uint32_t cnt = misc[2];
    uint32_t n2;

    if (cnt >= RSEL && cnt <= FINCAP) {
        // ======== FAST PATH: all candidates are finalists; no radix at all ====
        for (uint32_t i = tid; i < cnt; i += NT) {
            uint64_t e = sel[i];
            uint32_t k = (uint32_t)(e >> 32);
            uint32_t bits = (k & 0x80000000u) ? (k & 0x7FFFFFFFu) : ~k;
            float x  = __uint_as_float(bits);
            float sc = 1.0f / (1.0f + expf(-x));
            sel2[i] = ((uint64_t)__float_as_uint(sc) << 32) | (uint64_t)(uint32_t)e;
        }
        n2 = cnt;
    } else {
        // ======== SLOW PATH (exactness fallback; ~never taken) ========
        for (int i = tid; i < NB1; i += NT) hist[i] = 0;
        if (tid == 0) misc[2] = 0;
        __syncthreads();
        for (int i4 = tid; i4 < NF4; i4 += NT) {
            float4 v = lg4[i4];
            atomicAdd(&hist[xform(__float_as_uint(v.x)) >> SH1], 1u);
            atomicAdd(&hist[xform(__float_as_uint(v.y)) >> SH1], 1u);
            atomicAdd(&hist[xform(__float_as_uint(v.z)) >> SH1], 1u);
            atomicAdd(&hist[xform(__float_as_uint(v.w)) >> SH1], 1u);
        }
        __syncthreads();
        uint32_t b1, r1;
        pick<NB1, true>(hist, part, gsufx, misc, tid, RSEL, &b1, &r1);  // re-zeroes hist
        for (int i4 = tid; i4 < NF4; i4 += NT) {
            float4 v = lg4[i4];
            uint32_t kk[4] = { xform(__float_as_uint(v.x)), xform(__float_as_uint(v.y)),
                               xform(__float_as_uint(v.z)), xform(__float_as_uint(v.w)) };
#pragma unroll
            for (int c = 0; c < 4; ++c) {
                uint32_t k = kk[c];
                uint32_t bk = k >> SH1;
                if (bk >= b1) {
                    uint32_t pos = atomicAdd(&misc[2], 1u);
                    uint32_t idx = 4u * (uint32_t)i4 + (uint32_t)c;
                    if (pos < SELCAP)
                        sel[pos] = ((uint64_t)k << 32) | (uint64_t)(0xFFFFFFFFu - idx);
                    if (bk == b1) atomicAdd(&hist[(k >> SH2) & 0xFFu], 1u);
                }
            }
        }
        __syncthreads();
        uint32_t t2, r2;
        pick<256, false>(hist, part, gsufx, misc, tid, r1, &t2, &r2);
        (void)r2;
        const uint32_t T2 = (b1 << SH1) | (t2 << SH2);
        uint32_t c2 = misc[2];
        uint32_t n = c2 > SELCAP ? SELCAP : c2;
        for (uint32_t i = tid; i < n; i += NT) {
            uint64_t e = sel[i];
            uint32_t k = (uint32_t)(e >> 32);
            if (k >= T2) {
                uint32_t bits = (k & 0x80000000u) ? (k & 0x7FFFFFFFu) : ~k;
                float x  = __uint_as_float(bits);
                float sc = 1.0f / (1.0f + expf(-x));
                uint32_t pos = atomicAdd(&misc[3], 1u);
                if (pos < FINCAP)
                    sel2[pos] = ((uint64_t)__float_as_uint(sc) << 32) | (uint64_t)(uint32_t)e;
            }
        }
        __syncthreads();
        uint32_t m3 = misc[3];
        n2 = m3 > FINCAP ? FINCAP : m3;
    }
    __syncthreads();

    // ---- exact rank by (score desc, idx asc) + fused epilogue ----
    for (uint32_t i = tid; i < n2; i += NT) {
        uint64_t my = sel2[i];
        uint32_t rank = 0;
        for (uint32_t j = 0; j < n2; ++j)
            rank += (sel2[j] > my) ? 1u : 0u;
        if (rank < TOPK) {
            uint32_t idx = 0xFFFFFFFFu - (uint32_t)(my & 0xFFFFFFFFull);
            uint32_t lab = idx % NC;
            uint32_t q   = idx / NC;
            float4 bx = reinterpret_cast<const float4*>(pboxes)[(size_t)b * NQ + q];
            float sw = sizes[2 * b + 0];
            float sh = sizes[2 * b + 1];
            float hw = 0.5f * bx.z, hh = 0.5f * bx.w;
            float4 o;
            o.x = (bx.x - hw) * sw;
            o.y = (bx.y - hh) * sh;
            o.z = (bx.x + hw) * sw;
            o.w = (bx.y + hh) * sh;
            out[(size_t)b * TOPK + rank] = (float)lab;                                    // labels
            reinterpret_cast<float4*>(out + (size_t)NBATCH * TOPK)[(size_t)b * TOPK + rank] = o; // boxes
            out[(size_t)NBATCH * TOPK * 5 + (size_t)b * TOPK + rank] =
                __uint_as_float((uint32_t)(my >> 32));                                    // scores
        }
    }
}

extern "C" void kernel_launch(void* const* d_in, const int* in_sizes, int n_in,
                              void* d_out, int out_size, void* d_ws, size_t ws_size,
                              hipStream_t stream) {
    const float* logits = (const float*)d_in[0];   // [1024,300,80] f32
    const float* pboxes = (const float*)d_in[1];   // [1024,300,4]  f32
    const float* sizes  = (const float*)d_in[2];   // [1024,2]      f32
    float* out = (float*)d_out;                    // labels | boxes | scores (flat f32)

    hipLaunchKernelGGL(rtdetr_post_kernel, dim3(NBATCH), dim3(NT), 0, stream,
                       logits, pboxes, sizes, out);
}

// Round 8
// 25.252 us; speedup vs baseline: 2.0554x; 2.0554x over previous
//
#include <hip/hip_runtime.h>
#include <stdint.h>

// Problem constants
#define NBATCH 1024
#define NQ 300
#define NC 80
#define QC 24000       // NQ * NC floats per batch
#define NF4 6000       // QC / 4
#define TOPK 300
#define RSEL 384u      // fast-path lower guard / slow-path select rank
#define NT 512         // threads per block (8 waves)
#define NB1 2048       // slow-path coarse histogram buckets (key bits [31:21])
#define SH1 21
#define SH2 13         // slow-path refine bucket = (key >> 13) & 0xFF
#define SELCAP 2048    // candidate buffer
#define FINCAP 768     // finalist cap / fast-path upper guard
#define TAIL 368       // threads with a valid 12th float4 (6000 - 11*512)
#define THRESH 2.0f    // prefilter: candidate iff logit >= 2.0 (E[cnt]~546, sigma~23)
#define NBH 2048       // rank histogram buckets over score bits [20:10]
#define SBASE 0x3F600000u

// order-preserving f32-bits -> u32 key (branchless)
__device__ __forceinline__ uint32_t xform(uint32_t u) {
    return u ^ (uint32_t)(((int32_t)u >> 31) | 0x80000000);
}

// monotone bucket map for score bits (all fast-path scores in [0.8808, 1.0))
__device__ __forceinline__ uint32_t sbucket(uint32_t sbits) {
    int32_t d = (int32_t)(sbits - SBASE);
    d = d < 0 ? 0 : d;
    uint32_t bkt = ((uint32_t)d) >> 10;
    return bkt > (NBH - 1) ? (NBH - 1) : bkt;
}

// ---------------------------------------------------------------------------
// pick<NB,ZERO> (slow path only): hist[NB] finalized -> bucket from the top
// containing the rem-th largest + residual inside it. ZERO re-zeroes hist.
// ---------------------------------------------------------------------------
template<int NB, bool ZERO>
__device__ __forceinline__ void pick(uint32_t* __restrict__ hist,
                                     uint32_t* __restrict__ part,
                                     uint32_t* __restrict__ gsufx,
                                     uint32_t* __restrict__ misc,
                                     int tid, uint32_t rem,
                                     uint32_t* bucket_out, uint32_t* rem_out) {
    constexpr int G = (NB >= NT) ? (NB / NT) : 1;
    const int base = tid * G;
    uint32_t h[G];
    uint32_t s = 0;
    if (base < NB) {
#pragma unroll
        for (int u = 0; u < G; ++u) { h[u] = hist[base + u]; s += h[u]; }
        if (ZERO) {
#pragma unroll
            for (int u = 0; u < G; ++u) hist[base + u] = 0;
        }
    } else {
#pragma unroll
        for (int u = 0; u < G; ++u) h[u] = 0;
    }
    part[tid] = s;
    __syncthreads();

    if (tid < 64) {
        uint32_t gs = 0;
#pragma unroll
        for (int u = 0; u < 8; ++u) gs += part[(tid << 3) + u];
        uint32_t S = gs;
#pragma unroll
        for (int off = 1; off < 64; off <<= 1) {
            uint32_t v = __shfl_down(S, off, 64);
            if (tid + off < 64) S += v;
        }
        gsufx[tid] = S;
        if (tid == 0) gsufx[64] = 0;
    }
    __syncthreads();

    const int g8 = tid >> 3;
    uint32_t A = gsufx[g8 + 1];
    for (int t2 = tid + 1; t2 < ((g8 + 1) << 3); ++t2) A += part[t2];
    if (base < NB && A < rem && A + s >= rem) {
        uint32_t acc = 0, bsel = (uint32_t)base, r = 1;
#pragma unroll
        for (int u = G - 1; u >= 0; --u) {
            if (A + acc + h[u] >= rem) { bsel = (uint32_t)(base + u); r = rem - A - acc; break; }
            acc += h[u];
        }
        misc[0] = bsel;
        misc[1] = r;
    }
    __syncthreads();
    *bucket_out = misc[0];
    *rem_out    = misc[1];
}

__global__ void __launch_bounds__(NT, 6)
rtdetr_post_kernel(const float* __restrict__ logits, const float* __restrict__ pboxes,
                   const float* __restrict__ sizes, float* __restrict__ out) {
    __shared__ __align__(16) uint32_t hist[NBH + 1];  // 8.2KB (+sentinel, stays 0)
    __shared__ uint64_t sel[SELCAP];                  // 16KB: candidates, then bucket-sorted keys
    __shared__ uint64_t sel2[FINCAP];                 // 6KB finalist (score,~idx) keys
    __shared__ uint32_t part[NT];                     // 2KB
    __shared__ uint32_t gsufx[65];
    __shared__ uint32_t misc[4];

    const int tid = threadIdx.x;
    const int b   = blockIdx.x;
    const float4* lg4 = reinterpret_cast<const float4*>(logits + (size_t)b * QC);

    // ---- init: zero hist + counters (hist used only after 2+ barriers) ----
    for (int i = tid; i <= NBH; i += NT) hist[i] = 0;
    if (tid == 0) { misc[2] = 0; misc[3] = 0; }
    __syncthreads();

    // ---- stream + prefilter: 1 v_cmp per element; xform/push only on hits ----
#pragma unroll
    for (int k = 0; k < 12; ++k) {
        if (k < 11 || tid < TAIL) {
            float4 v = lg4[tid + (k << 9)];
            const uint32_t i4 = (uint32_t)(tid + (k << 9));
            float f[4] = { v.x, v.y, v.z, v.w };
#pragma unroll
            for (int c = 0; c < 4; ++c) {
                if (f[c] >= THRESH) {
                    uint32_t key = xform(__float_as_uint(f[c]));
                    uint32_t pos = atomicAdd(&misc[2], 1u);
                    uint32_t idx = 4u * i4 + (uint32_t)c;
                    if (pos < SELCAP)
                        sel[pos] = ((uint64_t)key << 32) | (uint64_t)(0xFFFFFFFFu - idx);
                }
            }
        }
    }
    __syncthreads();

    const uint32_t cnt = misc[2];
    uint32_t n2;

    if (cnt >= RSEL && cnt <= FINCAP) {
        // ==== FAST PATH: all candidates are finalists; sigmoid -> sel2 ====
        for (uint32_t i = tid; i < cnt; i += NT) {
            uint64_t e = sel[i];
            uint32_t k = (uint32_t)(e >> 32);
            uint32_t bits = (k & 0x80000000u) ? (k & 0x7FFFFFFFu) : ~k;
            float x  = __uint_as_float(bits);
            float sc = 1.0f / (1.0f + expf(-x));
            sel2[i] = ((uint64_t)__float_as_uint(sc) << 32) | (uint64_t)(uint32_t)e;
        }
        n2 = cnt;
    } else {
        // ==== SLOW PATH (exactness fallback; ~never taken) ====
        for (int i4 = tid; i4 < NF4; i4 += NT) {
            float4 v = lg4[i4];
            atomicAdd(&hist[xform(__float_as_uint(v.x)) >> SH1], 1u);
            atomicAdd(&hist[xform(__float_as_uint(v.y)) >> SH1], 1u);
            atomicAdd(&hist[xform(__float_as_uint(v.z)) >> SH1], 1u);
            atomicAdd(&hist[xform(__float_as_uint(v.w)) >> SH1], 1u);
        }
        __syncthreads();
        uint32_t b1, r1;
        pick<NB1, true>(hist, part, gsufx, misc, tid, RSEL, &b1, &r1);  // re-zeroes hist
        if (tid == 0) misc[2] = 0;
        __syncthreads();
        for (int i4 = tid; i4 < NF4; i4 += NT) {
            float4 v = lg4[i4];
            uint32_t kk[4] = { xform(__float_as_uint(v.x)), xform(__float_as_uint(v.y)),
                               xform(__float_as_uint(v.z)), xform(__float_as_uint(v.w)) };
#pragma unroll
            for (int c = 0; c < 4; ++c) {
                uint32_t k = kk[c];
                uint32_t bk = k >> SH1;
                if (bk >= b1) {
                    uint32_t pos = atomicAdd(&misc[2], 1u);
                    uint32_t idx = 4u * (uint32_t)i4 + (uint32_t)c;
                    if (pos < SELCAP)
                        sel[pos] = ((uint64_t)k << 32) | (uint64_t)(0xFFFFFFFFu - idx);
                    if (bk == b1) atomicAdd(&hist[(k >> SH2) & 0xFFu], 1u);
                }
            }
        }
        __syncthreads();
        uint32_t t2, r2;
        pick<256, false>(hist, part, gsufx, misc, tid, r1, &t2, &r2);
        (void)r2;
        const uint32_t T2 = (b1 << SH1) | (t2 << SH2);
        uint32_t c2 = misc[2];
        uint32_t nn = c2 > SELCAP ? SELCAP : c2;
        for (uint32_t i = tid; i < nn; i += NT) {
            uint64_t e = sel[i];
            uint32_t k = (uint32_t)(e >> 32);
            if (k >= T2) {
                uint32_t bits = (k & 0x80000000u) ? (k & 0x7FFFFFFFu) : ~k;
                float x  = __uint_as_float(bits);
                float sc = 1.0f / (1.0f + expf(-x));
                uint32_t pos = atomicAdd(&misc[3], 1u);
                if (pos < FINCAP)
                    sel2[pos] = ((uint64_t)__float_as_uint(sc) << 32) | (uint64_t)(uint32_t)e;
            }
        }
        __syncthreads();
        uint32_t m3 = misc[3];
        n2 = m3 > FINCAP ? FINCAP : m3;
        // re-zero hist (dirty from radix) for the common counting-rank
        for (int i = tid; i < 256; i += NT) hist[i] = 0;   // pick<256,false> region
    }
    __syncthreads();

    // ==== common counting rank over sel2[0..n2): O(n) instead of O(n^2) ====
    // 1) histogram score buckets
    for (uint32_t i = tid; i < n2; i += NT)
        atomicAdd(&hist[sbucket((uint32_t)(sel2[i] >> 32))], 1u);
    __syncthreads();

    // 2) suffix scan: hist[b] <- G[b] = #elements in buckets > b
    {
        const int base = tid * (NBH / NT);                // 4 buckets/thread
        uint32_t h0 = hist[base], h1 = hist[base + 1], h2 = hist[base + 2], h3 = hist[base + 3];
        part[tid] = h0 + h1 + h2 + h3;
        __syncthreads();
        if (tid < 64) {
            uint32_t gs = 0;
#pragma unroll
            for (int u = 0; u < 8; ++u) gs += part[(tid << 3) + u];
            uint32_t S = gs;
#pragma unroll
            for (int off = 1; off < 64; off <<= 1) {
                uint32_t v = __shfl_down(S, off, 64);
                if (tid + off < 64) S += v;
            }
            gsufx[tid] = S;
            if (tid == 0) gsufx[64] = 0;
        }
        __syncthreads();
        const int g8 = tid >> 3;
        uint32_t A = gsufx[g8 + 1];
        for (int t2 = tid + 1; t2 < ((g8 + 1) << 3); ++t2) A += part[t2];
        hist[base + 3] = A;
        hist[base + 2] = A + h3;
        hist[base + 1] = A + h3 + h2;
        hist[base + 0] = A + h3 + h2 + h1;
    }
    __syncthreads();

    // 3) scatter into bucket-sorted order (desc buckets); hist[b] -> S[b]
    for (uint32_t i = tid; i < n2; i += NT) {
        uint64_t k = sel2[i];
        uint32_t slot = atomicAdd(&hist[sbucket((uint32_t)(k >> 32))], 1u);
        sel[slot] = k;
    }
    __syncthreads();

    // 4) exact rank = G[b] + #same-bucket peers with greater (score,~idx) key
    for (uint32_t i = tid; i < n2; i += NT) {
        uint64_t my = sel2[i];
        uint32_t bkt = sbucket((uint32_t)(my >> 32));
        uint32_t seg0 = hist[bkt + 1];      // post-scatter S[b+1] = G[b]
        uint32_t seg1 = hist[bkt];          // post-scatter S[b]
        uint32_t rank = seg0;
        for (uint32_t j = seg0; j < seg1; ++j)
            rank += (sel[j] > my) ? 1u : 0u;
        if (rank < TOPK) {
            uint32_t idx = 0xFFFFFFFFu - (uint32_t)(my & 0xFFFFFFFFull);
            uint32_t lab = idx % NC;
            uint32_t q   = idx / NC;
            float4 bx = reinterpret_cast<const float4*>(pboxes)[(size_t)b * NQ + q];
            float sw = sizes[2 * b + 0];
            float sh = sizes[2 * b + 1];
            float hw = 0.5f * bx.z, hh = 0.5f * bx.w;
            float4 o;
            o.x = (bx.x - hw) * sw;
            o.y = (bx.y - hh) * sh;
            o.z = (bx.x + hw) * sw;
            o.w = (bx.y + hh) * sh;
            out[(size_t)b * TOPK + rank] = (float)lab;                                    // labels
            reinterpret_cast<float4*>(out + (size_t)NBATCH * TOPK)[(size_t)b * TOPK + rank] = o; // boxes
            out[(size_t)NBATCH * TOPK * 5 + (size_t)b * TOPK + rank] =
                __uint_as_float((uint32_t)(my >> 32));                                    // scores
        }
    }
}

extern "C" void kernel_launch(void* const* d_in, const int* in_sizes, int n_in,
                              void* d_out, int out_size, void* d_ws, size_t ws_size,
                              hipStream_t stream) {
    const float* logits = (const float*)d_in[0];   // [1024,300,80] f32
    const float* pboxes = (const float*)d_in[1];   // [1024,300,4]  f32
    const float* sizes  = (const float*)d_in[2];   // [1024,2]      f32
    float* out = (float*)d_out;                    // labels | boxes | scores (flat f32)

    hipLaunchKernelGGL(rtdetr_post_kernel, dim3(NBATCH), dim3(NT), 0, stream,
                       logits, pboxes, sizes, out);
}